// Round 2
// baseline (253.866 us; speedup 1.0000x reference)
//
#include <hip/hip_runtime.h>

// SSIM map — wave-autonomous rolling-register kernel.
// B=16, C=3, H=W=512, 11-tap separable gaussian (sigma=1.5).
//
// One 64-thread block (= one wave) produces a 64-col x 64-row output band.
// Per input row: coalesced load of 74 cols (64 lanes + 10 halo via lanes 0..9)
// -> 640 B LDS line buffer -> horizontal 11-tap conv of 5 fields (x, y, xx,
// yy, xy) in registers -> vertical 11-tap conv via 11x5 rolling register
// accumulators (static slot indexing from the unrolled 11-phase inner loop)
// -> SSIM epilogue with v_rcp_f32 -> coalesced store.
// No hf[] LDS array, no cross-wave barriers, 55 fewer LDS reads per pixel.

#define W   512
#define H   512
#define BC  48
#define RPB 64            // output rows per wave
#define NS  (W / 64)      // 8 col strips
#define NB  (H / RPB)     // 8 row bands

__global__ __launch_bounds__(64) void ssim_kernel(
    const float* __restrict__ x, const float* __restrict__ y,
    float* __restrict__ out)
{
    __shared__ float bufx[80];   // input cols col0-5 .. col0+68 (74 used)
    __shared__ float bufy[80];

    // fp32-normalized gaussian, sigma=1.5, K=11 (matches np reference ~1e-7)
    const float g[11] = {
        0.00102838f, 0.00759875f, 0.03600077f, 0.10936069f, 0.21300553f,
        0.26601172f,
        0.21300553f, 0.10936069f, 0.03600077f, 0.00759875f, 0.00102838f};

    const int lane  = threadIdx.x;   // 0..63, output col within strip
    const int strip = blockIdx.x;    // 0..7
    const int band  = blockIdx.y;    // 0..7
    const int bc    = blockIdx.z;    // 0..47

    const int col0 = strip * 64;
    const int r0   = band * RPB;

    const float* __restrict__ xp = x + (size_t)bc * H * W;
    const float* __restrict__ yp = y + (size_t)bc * H * W;
    float* __restrict__ op = out + (size_t)bc * H * W + col0 + lane;

    const int  gc   = col0 - 5 + lane;            // this lane's load col
    const bool cok  = (gc >= 0) && (gc < W);
    const int  gc2  = gc + 64;                    // halo col (lanes 0..9)
    const bool cok2 = (lane < 10) && (gc2 < W);

    // rolling vertical accumulators: slot j holds the in-flight output row
    // with (o - r0 + 5) mod 11 == j; 5 fields each
    float acc[11][5];
#pragma unroll
    for (int j = 0; j < 11; ++j)
#pragma unroll
        for (int f = 0; f < 5; ++f) acc[j][f] = 0.f;

    // input rows rr = 0..73  ->  r = r0-5 .. r0+68
#pragma unroll 1
    for (int outer = 0; outer < 7; ++outer) {
#pragma unroll
        for (int ph = 0; ph < 11; ++ph) {
            const int rr = outer * 11 + ph;
            if (rr < 74) {                       // wave-uniform guard
                const int  r   = r0 - 5 + rr;
                const bool rok = (r >= 0) && (r < H);

                float vx = 0.f, vy = 0.f, vx2 = 0.f, vy2 = 0.f;
                if (rok) {
                    const float* __restrict__ xr = xp + (size_t)r * W;
                    const float* __restrict__ yr = yp + (size_t)r * W;
                    if (cok)  { vx  = xr[gc];  vy  = yr[gc];  }
                    if (cok2) { vx2 = xr[gc2]; vy2 = yr[gc2]; }
                }

                __syncthreads();                 // WAR vs previous row's reads
                bufx[lane] = vx;
                bufy[lane] = vy;
                if (lane < 10) { bufx[64 + lane] = vx2; bufy[64 + lane] = vy2; }
                __syncthreads();                 // RAW: writes visible

                // horizontal 11-tap conv at output col col0+lane
                float hx = 0.f, hy = 0.f, hxx = 0.f, hyy = 0.f, hxy = 0.f;
#pragma unroll
                for (int k = 0; k < 11; ++k) {
                    const float w  = g[k];
                    const float ax = bufx[lane + k];
                    const float ay = bufy[lane + k];
                    hx  += w * ax;
                    hy  += w * ay;
                    hxx += w * (ax * ax);
                    hyy += w * (ay * ay);
                    hxy += w * (ax * ay);
                }

                // vertical accumulate into all 11 pending output rows.
                // input row r contributes to output o = r-d, d in -5..5,
                // with weight g[d+5]; slot j -> d = centered((ph-j) mod 11),
                // so weight index m = (ph - j + 16) mod 11.
#pragma unroll
                for (int j = 0; j < 11; ++j) {
                    const int   m = (ph - j + 16) % 11;
                    const float w = g[m];
                    acc[j][0] += w * hx;
                    acc[j][1] += w * hy;
                    acc[j][2] += w * hxx;
                    acc[j][3] += w * hyy;
                    acc[j][4] += w * hxy;
                }

                // slot (ph+6)%11 just received its d=+5 tap: output o = r-5
                const int jc = (ph + 6) % 11;
                if (rr >= 10) {                  // o in [r0, r0+63]
                    const float mu1   = acc[jc][0];
                    const float mu2   = acc[jc][1];
                    const float mu1sq = mu1 * mu1;
                    const float mu2sq = mu2 * mu2;
                    const float mu12  = mu1 * mu2;
                    const float s1    = acc[jc][2] - mu1sq;
                    const float s2    = acc[jc][3] - mu2sq;
                    const float s12   = acc[jc][4] - mu12;
                    const float num = (2.f * mu12 + 1e-4f) * (2.f * s12 + 9e-4f);
                    const float den = (mu1sq + mu2sq + 1e-4f) * (s1 + s2 + 9e-4f);
                    op[(size_t)(r - 5) * W] = num * __builtin_amdgcn_rcpf(den);
                }
#pragma unroll
                for (int f = 0; f < 5; ++f) acc[jc][f] = 0.f;
            }
        }
    }
}

extern "C" void kernel_launch(void* const* d_in, const int* in_sizes, int n_in,
                              void* d_out, int out_size, void* d_ws, size_t ws_size,
                              hipStream_t stream) {
    const float* img_out    = (const float*)d_in[0];
    const float* img_target = (const float*)d_in[1];
    // d_in[2] is window_size==11; fixed by the problem, baked into the kernel.
    float* out = (float*)d_out;

    dim3 grid(NS, NB, BC);   // 8 x 8 x 48 = 3072 one-wave blocks
    ssim_kernel<<<grid, 64, 0, stream>>>(img_out, img_target, out);
}